// Round 2
// baseline (4294.482 us; speedup 1.0000x reference)
//
#include <hip/hip_runtime.h>

// K-means, B=16, N=96*96=9216, C=256, K=21, 20 iterations.
// Structure: decode_idx; gather_init; 20x { assign; accumulate; finalize }.
// cent lives in d_out (finalize updates in place -> final state is the answer).
// finalize re-zeroes sums/counts and recomputes csq for the next iteration, so
// no memsets are needed and every launch does identical work (graph-safe).
//
// R1 fix: init_idx is int64 in the reference (jax.random.randint(dtype=jnp.int64));
// reading it as int32 gathered wrong initial centroids -> absmax 0.155. decode_idx
// auto-detects int64 vs int32 layout and writes clean int32 indices to ws.

#define BB 16
#define NN 9216
#define CC 256
#define KK 21
#define ITERS 20

// ---------------------------------------------------------------- decode_idx
// One block. If all int64-interpreted values are in [0,NN), data is int64;
// otherwise treat as int32. Writes BB*KK decoded int32 indices.
__global__ __launch_bounds__(512) void decode_idx(
    const void* __restrict__ raw, int* __restrict__ out) {
  __shared__ int all_ok;
  if (threadIdx.x == 0) all_ok = 1;
  __syncthreads();
  const long long* p64 = (const long long*)raw;
  const int* p32 = (const int*)raw;
  int t = threadIdx.x;
  long long v64 = 0;
  if (t < BB * KK) {
    v64 = p64[t];
    if (v64 < 0 || v64 >= NN) atomicAnd(&all_ok, 0);
  }
  __syncthreads();
  if (t < BB * KK) out[t] = all_ok ? (int)v64 : p32[t];
}

// ---------------------------------------------------------------- gather_init
// One block per (b,k): gather initial centroid, compute ||c||^2, zero sums/counts.
__global__ __launch_bounds__(256) void gather_init(
    const float* __restrict__ x, const int* __restrict__ idx_dec,
    float* __restrict__ cent, float* __restrict__ csq,
    float* __restrict__ sums, float* __restrict__ counts) {
  int bk = blockIdx.x;          // 0..B*K-1
  int b = bk / KK;
  int c = threadIdx.x;          // 0..255
  int idx = idx_dec[bk];
  float v = x[((size_t)b * NN + idx) * CC + c];
  cent[(size_t)bk * CC + c] = v;
  sums[(size_t)bk * CC + c] = 0.f;
  float s = v * v;
  #pragma unroll
  for (int off = 32; off > 0; off >>= 1) s += __shfl_down(s, off, 64);
  __shared__ float red[4];
  int w = threadIdx.x >> 6, lane = threadIdx.x & 63;
  if (lane == 0) red[w] = s;
  __syncthreads();
  if (threadIdx.x == 0) {
    csq[bk] = red[0] + red[1] + red[2] + red[3];
    counts[bk] = 0.f;
  }
}

// ---------------------------------------------------------------- assign
// One thread per point. Centroid reads are wave-uniform -> scalar loads.
// d_k = ||x||^2 - 2 x.c_k + ||c_k||^2, first-min tie-break (matches argmin).
__global__ __launch_bounds__(256) void assign_kernel(
    const float* __restrict__ x, const float* __restrict__ cent,
    const float* __restrict__ csq, int* __restrict__ assign) {
  const int nb = NN / 256;      // 36 blocks per batch
  int b = blockIdx.x / nb;
  int n = (blockIdx.x % nb) * 256 + threadIdx.x;
  const float* xp = x + ((size_t)b * NN + n) * CC;
  const float* cp = cent + (size_t)b * KK * CC;
  const float* cq = csq + b * KK;

  float dot[KK];
  #pragma unroll
  for (int k = 0; k < KK; ++k) dot[k] = 0.f;
  float xsq = 0.f;

  for (int c0 = 0; c0 < CC; c0 += 16) {
    float xv[16];
    #pragma unroll
    for (int j = 0; j < 16; j += 4) {
      float4 t = *(const float4*)(xp + c0 + j);
      xv[j] = t.x; xv[j + 1] = t.y; xv[j + 2] = t.z; xv[j + 3] = t.w;
    }
    #pragma unroll
    for (int j = 0; j < 16; ++j) xsq = fmaf(xv[j], xv[j], xsq);
    #pragma unroll
    for (int k = 0; k < KK; ++k) {
      const float* cpk = cp + k * CC + c0;   // wave-uniform address
      #pragma unroll
      for (int j = 0; j < 16; ++j) dot[k] = fmaf(xv[j], cpk[j], dot[k]);
    }
  }

  float best = INFINITY;
  int bestk = 0;
  #pragma unroll
  for (int k = 0; k < KK; ++k) {
    float d = xsq - 2.f * dot[k] + cq[k];
    if (d < best) { best = d; bestk = k; }
  }
  assign[(size_t)b * NN + n] = bestk;
}

// ---------------------------------------------------------------- accumulate
// One wave per point at a time (lanes cover 64 float4 channel-slices).
// Per-wave private LDS sums (race-free, no atomics inner loop); block merge +
// global fp32 atomics at the end.
__global__ __launch_bounds__(128) void accumulate(
    const float* __restrict__ x, const int* __restrict__ assign,
    float* __restrict__ sums, float* __restrict__ counts) {
  __shared__ float lsum[2][KK][CC];   // 43008 B
  __shared__ float lcnt[2][KK];
  const int blocksPerBatch = 16;
  int b = blockIdx.x / blocksPerBatch;
  int chunk = blockIdx.x % blocksPerBatch;
  int w = threadIdx.x >> 6, lane = threadIdx.x & 63;

  for (int i = threadIdx.x; i < 2 * KK * CC; i += 128) ((float*)lsum)[i] = 0.f;
  for (int i = threadIdx.x; i < 2 * KK; i += 128) ((float*)lcnt)[i] = 0.f;
  __syncthreads();

  const int pts = NN / blocksPerBatch;   // 576 points per block
  const int perWave = pts / 2;           // 288 per wave
  int n0 = chunk * pts + w * perWave;
  for (int i = 0; i < perWave; ++i) {
    int n = n0 + i;
    int k = assign[b * NN + n];          // wave-uniform value
    const float4 v = *(const float4*)(x + ((size_t)b * NN + n) * CC + lane * 4);
    float* dst = &lsum[w][k][lane * 4];  // contiguous 1KB per wave: conflict-free
    float4 cur = *(float4*)dst;
    cur.x += v.x; cur.y += v.y; cur.z += v.z; cur.w += v.w;
    *(float4*)dst = cur;
    if (lane == 0) lcnt[w][k] += 1.f;
  }
  __syncthreads();

  for (int i = threadIdx.x; i < KK * CC; i += 128) {
    float vsum = (&lsum[0][0][0])[i] + (&lsum[1][0][0])[i];
    atomicAdd(&sums[(size_t)b * KK * CC + i], vsum);
  }
  for (int i = threadIdx.x; i < KK; i += 128) {
    atomicAdd(&counts[b * KK + i], lcnt[0][i] + lcnt[1][i]);
  }
}

// ---------------------------------------------------------------- finalize
// One block per (b,k): cent = counts>0 ? sums/max(counts,1) : cent (in place),
// recompute csq, zero sums/counts for the next iteration.
__global__ __launch_bounds__(256) void finalize(
    float* __restrict__ cent, float* __restrict__ sums,
    float* __restrict__ counts, float* __restrict__ csq) {
  int bk = blockIdx.x;
  int c = threadIdx.x;
  float cnt = counts[bk];
  float s = sums[(size_t)bk * CC + c];
  float old = cent[(size_t)bk * CC + c];
  float nc = (cnt > 0.f) ? (s / fmaxf(cnt, 1.f)) : old;
  cent[(size_t)bk * CC + c] = nc;
  sums[(size_t)bk * CC + c] = 0.f;

  float sq = nc * nc;
  #pragma unroll
  for (int off = 32; off > 0; off >>= 1) sq += __shfl_down(sq, off, 64);
  __shared__ float red[4];
  int w = threadIdx.x >> 6, lane = threadIdx.x & 63;
  if (lane == 0) red[w] = sq;
  __syncthreads();
  if (threadIdx.x == 0) {
    csq[bk] = red[0] + red[1] + red[2] + red[3];
    counts[bk] = 0.f;
  }
}

// ---------------------------------------------------------------- launch
extern "C" void kernel_launch(void* const* d_in, const int* in_sizes, int n_in,
                              void* d_out, int out_size, void* d_ws, size_t ws_size,
                              hipStream_t stream) {
  const float* x = (const float*)d_in[0];
  float* cent = (float*)d_out;                 // [B,K,C] working + final output

  char* ws = (char*)d_ws;
  int* assign = (int*)ws;                              // B*N ints   (589824 B)
  float* sums = (float*)(ws + (size_t)BB * NN * 4);    // B*K*C      (344064 B)
  float* counts = sums + (size_t)BB * KK * CC;         // B*K        (1344 B)
  float* csq = counts + BB * KK;                       // B*K        (1344 B)
  int* idx_dec = (int*)(csq + BB * KK);                // B*K        (1344 B)

  decode_idx<<<1, 512, 0, stream>>>(d_in[1], idx_dec);
  gather_init<<<BB * KK, 256, 0, stream>>>(x, idx_dec, cent, csq, sums, counts);
  for (int it = 0; it < ITERS; ++it) {
    assign_kernel<<<BB * (NN / 256), 256, 0, stream>>>(x, cent, csq, assign);
    accumulate<<<BB * 16, 128, 0, stream>>>(x, assign, sums, counts);
    finalize<<<BB * KK, 256, 0, stream>>>(cent, sums, counts, csq);
  }
}